// Round 16
// baseline (22.677 us; speedup 1.0000x reference)
//
#include <hip/hip_runtime.h>
#include <hip/hip_bf16.h>

#define NB 16
#define NT 128
#define NR 8192
#define NC 91
#define XTH (0.7f / 1.7f)   // iou>0.7  <=>  inter/(areaA+areaB) > 0.7/1.7

#define TILES 4                              // 16-proposal tiles per block
#define GRID_MAIN (NB * NR / (16 * TILES))   // 2048 blocks -> up to 32 waves/CU
#define BLK_PER_B (GRID_MAIN / NB)           // 128

__device__ __forceinline__ float fastdiv(float a, float b) {
    return a * __builtin_amdgcn_rcpf(b);     // 1-ulp fast divide
}
__device__ __forceinline__ float smooth_l1(float x) {
    float ax = fabsf(x);
    return ax < 1.0f ? 0.5f * x * x : ax - 0.5f;
}

// DPP row-rotate (16-lane rows == our groups). VALU-only, no LDS pipe.
#define RORU(x, C) ((unsigned int)__builtin_amdgcn_update_dpp(0, (int)(x), (C), 0xF, 0xF, false))
#define RORF(x, C) __uint_as_float(RORU(__float_as_uint(x), (C)))

// One fused rotate-reduce step for the 3 chains (max, sum, max)
#define ROTSTEP(bu, sv, mv, C)                                                 \
    bu = max(bu, RORU(bu, C));                                                 \
    sv = sv + RORF(sv, C);                                                     \
    mv = fmaxf(mv, RORF(mv, C));

// Load one tile's data into register bank S (pure textual expansion).
#define LOADT(S, it_)                                                          \
    {                                                                          \
        const size_t p_ = pbase + (size_t)(it_) * 16;                          \
        pr##S = ((const float4*)nms_reg)[p_];                                  \
        const float* row_ = rcnn_cls + p_ * NC;                                \
        v##S##0 = row_[l];                                                     \
        v##S##1 = row_[l + 16];                                                \
        v##S##2 = row_[l + 32];                                                \
        v##S##3 = row_[l + 48];                                                \
        v##S##4 = row_[l + 64];                                                \
        v##S##5 = v5ok ? row_[c5] : -INFINITY;                                 \
    }

// Process bank S for tile T: rank-key IoU; CE (exp-sum + max) UNCONDITIONAL;
// all three group-reduces fused in one 4-step DPP rotate chain; stash result.
#define PROC(S, T)                                                             \
    {                                                                          \
        const float area_a = (pr##S.z - pr##S.x) * (pr##S.w - pr##S.y);        \
        unsigned int bu = 0u;                                                  \
        _Pragma("unroll")                                                      \
        for (int j = 0; j < 8; ++j) {                                          \
            const float4 t = tb[j];                                            \
            const float S_  = area_a + (t.z - t.x) * (t.w - t.y);              \
            const float itp = fmaxf(pr##S.x, t.x), il = fmaxf(pr##S.y, t.y);   \
            const float ib  = fminf(pr##S.z, t.z), ir = fminf(pr##S.w, t.w);   \
            const float inter = fmaxf(ib - itp, 0.f) * fmaxf(ir - il, 0.f);    \
            const float x = fastdiv(inter, S_);                                \
            bu = max(bu, (__float_as_uint(x) & 0xFFFFFF80u)                    \
                         | (127u - (unsigned int)(l + 16 * j)));               \
        }                                                                      \
        float sv = __expf(v##S##0) + __expf(v##S##1) + __expf(v##S##2)         \
                 + __expf(v##S##3) + __expf(v##S##4) + __expf(v##S##5);        \
        float mv = fmaxf(fmaxf(fmaxf(v##S##0, v##S##1),                        \
                               fmaxf(v##S##2, v##S##3)),                       \
                         fmaxf(v##S##4, v##S##5));                             \
        ROTSTEP(bu, sv, mv, 0x128)   /* ror 8 */                               \
        ROTSTEP(bu, sv, mv, 0x124)   /* ror 4 */                               \
        ROTSTEP(bu, sv, mv, 0x122)   /* ror 2 */                               \
        ROTSTEP(bu, sv, mv, 0x121)   /* ror 1 */                               \
        unsigned int meta = 0u;                                                \
        if (__uint_as_float(bu & 0xFFFFFF80u) > XTH) {                         \
            const int bidx = 127 - (int)(bu & 127u);                           \
            const int cls  = scls[bidx];                                       \
            meta = (unsigned int)bidx | 128u | ((unsigned int)cls << 9);       \
        }                                                                      \
        if (l == 0)                                                            \
            stash[w][((T) << 2) | (grp & 3)] =                                 \
                make_float4(__uint_as_float(meta), sv, mv, 0.f);               \
    }

__global__ __launch_bounds__(256) void frcnn_main(
    const float* __restrict__ nms_reg,
    const float* __restrict__ rcnn_reg,
    const float* __restrict__ rcnn_cls,
    const float* __restrict__ bboxes,
    const int* __restrict__ classes,
    const int* __restrict__ reduction,
    float4* __restrict__ part)
{
    __shared__ float4 sbox[NT];
    __shared__ int    scls[NT];
    __shared__ float4 stash[4][16];   // per-wave: 4 tiles x 4 groups
    __shared__ float4 sred[4];

    const int b     = blockIdx.x >> 7;            // 128 blocks per batch
    const int tile0 = (blockIdx.x & (BLK_PER_B - 1)) * TILES;
    const int grp   = threadIdx.x >> 4;           // 0..15
    const int l     = threadIdx.x & 15;
    const int w     = threadIdx.x >> 6;           // wave in block

    if (threadIdx.x < NT) {
        sbox[threadIdx.x] = ((const float4*)bboxes)[b * NT + threadIdx.x];
        scls[threadIdx.x] = classes[b * NT + threadIdx.x];
    }
    __syncthreads();

    // lane l's 8 target boxes (t = l+16j); areas recomputed inline
    float4 tb[8];
    #pragma unroll
    for (int j = 0; j < 8; ++j) tb[j] = sbox[l + 16 * j];

    const int rv = *reduction;
    float redv;
    if (rv >= 1 && rv <= 65536) redv = (float)rv; // int scalar (expected 16)
    else redv = __int_as_float(rv);               // defensive: f32-encoded
    const float rredv = __builtin_amdgcn_rcpf(redv);

    const int  c5   = l + 80;
    const bool v5ok = (c5 < NC);                  // l < 11

    const size_t pbase = (size_t)b * NR + (size_t)tile0 * 16 + grp;

    // register banks (named scalars only -- rule #20)
    float4 prA, prB;
    float vA0, vA1, vA2, vA3, vA4, vA5;
    float vB0, vB1, vB2, vB3, vB4, vB5;

    LOADT(A, 0)
    LOADT(B, 1)
    PROC(A, 0)
    LOADT(A, 2)
    PROC(B, 1)
    LOADT(B, 3)
    PROC(A, 2)
    PROC(B, 3)

    // ---- deferred epilogue: lanes 0..15 of each wave finalize 16 proposals ----
    // (stash written and read by the SAME wave -> no barrier needed)
    float cnt = 0.f, nll = 0.f, reg = 0.f, corr = 0.f;
    const int L = threadIdx.x & 63;
    if (L < 16) {
        const float4 st = stash[w][L];
        const unsigned int meta = __float_as_uint(st.x);
        if (meta & 128u) {
            const int bidx = (int)(meta & 127u);
            const int cls  = (int)((meta >> 9) & 127u);
            const int tl   = L >> 2;
            const size_t p = (size_t)b * NR + (size_t)(tile0 + tl) * 16
                           + (unsigned)(4 * w + (L & 3));
            const float lc = rcnn_cls[p * NC + cls];   // L2-hot re-load
            cnt  = 1.f;
            nll  = __logf(st.y) - lc;
            corr = (lc == st.z) ? 1.f : 0.f;           // == argmax match (no exact ties)

            const float4 bb = sbox[bidx];
            const float rd0 = rintf(bb.x * rredv) * redv;
            const float rd1 = rintf(bb.y * rredv) * redv;
            const float rd2 = rintf(bb.z * rredv) * redv;
            const float rd3 = rintf(bb.w * rredv) * redv;
            float hgt = rd2 - rd0; if (hgt == 0.f) hgt = 1.f;
            float wid = rd3 - rd1; if (wid == 0.f) wid = 1.f;
            const float rh = __builtin_amdgcn_rcpf(hgt);
            const float rw = __builtin_amdgcn_rcpf(wid);

            const float4 rr = ((const float4*)rcnn_reg)[p];
            reg = smooth_l1(rr.x - (bb.x - rd0) * rh)
                + smooth_l1(rr.y - (bb.y - rd1) * rw)
                + smooth_l1(rr.z - (bb.z - rd2) * rh)
                + smooth_l1(rr.w - (bb.w - rd3) * rw);
        }
    }

    // ---- width-16 butterfly (lanes 0..15 hold the values) ----
    #pragma unroll
    for (int mk = 8; mk; mk >>= 1) {
        cnt  += __shfl_xor(cnt,  mk, 16);
        nll  += __shfl_xor(nll,  mk, 16);
        reg  += __shfl_xor(reg,  mk, 16);
        corr += __shfl_xor(corr, mk, 16);
    }
    if (L == 0) sred[w] = make_float4(cnt, nll, reg, corr);
    __syncthreads();
    if (threadIdx.x == 0) {
        float4 t = make_float4(0.f, 0.f, 0.f, 0.f);
        #pragma unroll
        for (int i = 0; i < 4; ++i) {
            t.x += sred[i].x; t.y += sred[i].y; t.z += sred[i].z; t.w += sred[i].w;
        }
        part[blockIdx.x] = t;
    }
}

// Single-block tree reduce of the 2048 float4 partials + finalize.
__global__ __launch_bounds__(1024) void frcnn_reduce(
    const float4* __restrict__ part, float* __restrict__ out)
{
    __shared__ float4 sw[16];
    float4 s = make_float4(0.f, 0.f, 0.f, 0.f);
    for (int i = threadIdx.x; i < GRID_MAIN; i += 1024) {
        const float4 p = part[i];
        s.x += p.x; s.y += p.y; s.z += p.z; s.w += p.w;
    }
    #pragma unroll
    for (int off = 32; off > 0; off >>= 1) {
        s.x += __shfl_down(s.x, off);
        s.y += __shfl_down(s.y, off);
        s.z += __shfl_down(s.z, off);
        s.w += __shfl_down(s.w, off);
    }
    const int lane = threadIdx.x & 63;
    const int w    = threadIdx.x >> 6;
    if (lane == 0) sw[w] = s;
    __syncthreads();
    if (threadIdx.x == 0) {
        float4 t = make_float4(0.f, 0.f, 0.f, 0.f);
        #pragma unroll
        for (int i = 0; i < 16; ++i) {
            t.x += sw[i].x; t.y += sw[i].y; t.z += sw[i].z; t.w += sw[i].w;
        }
        const float pos   = (t.x > 0.f) ? 1.f : 0.f;
        const float denom = fmaxf(t.x, 1.f);
        out[0] = t.y / denom * pos;   // cls_loss
        out[1] = t.z / denom * pos;   // reg_loss
        out[2] = t.w / denom * pos;   // accuracy
    }
}

extern "C" void kernel_launch(void* const* d_in, const int* in_sizes, int n_in,
                              void* d_out, int out_size, void* d_ws, size_t ws_size,
                              hipStream_t stream) {
    // setup_inputs order: nms_reg, nms_cls(unused), rcnn_reg, rcnn_cls, bboxes, classes, reduction
    const float* nms_reg  = (const float*)d_in[0];
    const float* rcnn_reg = (const float*)d_in[2];
    const float* rcnn_cls = (const float*)d_in[3];
    const float* bboxes   = (const float*)d_in[4];
    const int*   classes  = (const int*)d_in[5];
    const int*   red      = (const int*)d_in[6];

    float4* part = (float4*)d_ws;   // 2048 * 16 B = 32 KiB, fully rewritten each launch

    frcnn_main<<<GRID_MAIN, 256, 0, stream>>>(nms_reg, rcnn_reg, rcnn_cls, bboxes,
                                              classes, red, part);
    frcnn_reduce<<<1, 1024, 0, stream>>>(part, (float*)d_out);
}

// Round 17
// 21.645 us; speedup vs baseline: 1.0477x; 1.0477x over previous
//
#include <hip/hip_runtime.h>
#include <hip/hip_bf16.h>

#define NB 16
#define NT 128
#define NR 8192
#define NC 91
#define XTH (0.7f / 1.7f)   // iou>0.7  <=>  inter/(areaA+areaB) > 0.7/1.7

#define TILES 8                              // 16-proposal tiles per block
#define GRID_MAIN (NB * NR / (16 * TILES))   // 1024 blocks
#define BLK_PER_B (GRID_MAIN / NB)           // 64

__device__ __forceinline__ float fastdiv(float a, float b) {
    return a * __builtin_amdgcn_rcpf(b);     // 1-ulp fast divide
}
__device__ __forceinline__ float smooth_l1(float x) {
    float ax = fabsf(x);
    return ax < 1.0f ? 0.5f * x * x : ax - 0.5f;
}

// DPP row-rotate (16-lane rows == our groups). VALU-only, no LDS pipe.
#define RORU(x, C) ((unsigned int)__builtin_amdgcn_update_dpp(0, (int)(x), (C), 0xF, 0xF, false))
#define RORF(x, C) __uint_as_float(RORU(__float_as_uint(x), (C)))

// One fused rotate-reduce step for the 3 chains (max, sum, max)
#define ROTSTEP(bu, sv, mv, C)                                                 \
    bu = max(bu, RORU(bu, C));                                                 \
    sv = sv + RORF(sv, C);                                                     \
    mv = fmaxf(mv, RORF(mv, C));

// Load one tile into bank S. Logit row read as 1 float4 (cols 4l..4l+3,
// dword-aligned: CDNA global dwordx4 needs only dword alignment) + 2 scalars
// (cols 64+l, 80+l). 4 VMEM instrs/tile/wave vs 7 scalar-only; f4 instr moves
// 1KB contiguous per wave -> wider HBM transactions for the demand-fetch.
#define LOADT(S, it_)                                                          \
    {                                                                          \
        const size_t p_ = pbase + (size_t)(it_) * 16;                          \
        pr##S = ((const float4*)nms_reg)[p_];                                  \
        const float* row_ = rcnn_cls + p_ * NC;                                \
        q##S = *(const float4*)(row_ + 4 * l);                                 \
        v##S##4 = row_[64 + l];                                                \
        v##S##5 = v5ok ? row_[80 + l] : -INFINITY;                             \
    }

// Process bank S for tile T: rank-key IoU; CE (exp-sum + max) over the lane's
// 6 values (layout-free: sum/max commutative); fused 4-step DPP rotate chain.
#define PROC(S, T)                                                             \
    {                                                                          \
        const float area_a = (pr##S.z - pr##S.x) * (pr##S.w - pr##S.y);        \
        unsigned int bu = 0u;                                                  \
        _Pragma("unroll")                                                      \
        for (int j = 0; j < 8; ++j) {                                          \
            const float4 t = tb[j];                                            \
            const float S_  = area_a + (t.z - t.x) * (t.w - t.y);              \
            const float itp = fmaxf(pr##S.x, t.x), il = fmaxf(pr##S.y, t.y);   \
            const float ib  = fminf(pr##S.z, t.z), ir = fminf(pr##S.w, t.w);   \
            const float inter = fmaxf(ib - itp, 0.f) * fmaxf(ir - il, 0.f);    \
            const float x = fastdiv(inter, S_);                                \
            bu = max(bu, (__float_as_uint(x) & 0xFFFFFF80u)                    \
                         | (127u - (unsigned int)(l + 16 * j)));               \
        }                                                                      \
        float sv = __expf(q##S.x) + __expf(q##S.y) + __expf(q##S.z)            \
                 + __expf(q##S.w) + __expf(v##S##4) + __expf(v##S##5);         \
        float mv = fmaxf(fmaxf(fmaxf(q##S.x, q##S.y),                          \
                               fmaxf(q##S.z, q##S.w)),                         \
                         fmaxf(v##S##4, v##S##5));                             \
        ROTSTEP(bu, sv, mv, 0x128)   /* ror 8 */                               \
        ROTSTEP(bu, sv, mv, 0x124)   /* ror 4 */                               \
        ROTSTEP(bu, sv, mv, 0x122)   /* ror 2 */                               \
        ROTSTEP(bu, sv, mv, 0x121)   /* ror 1 */                               \
        unsigned int meta = 0u;                                                \
        if (__uint_as_float(bu & 0xFFFFFF80u) > XTH) {                         \
            const int bidx = 127 - (int)(bu & 127u);                           \
            const int cls  = scls[bidx];                                       \
            meta = (unsigned int)bidx | 128u | ((unsigned int)cls << 9);       \
        }                                                                      \
        if (l == 0)                                                            \
            stash[w][((T) << 2) | (grp & 3)] =                                 \
                make_float4(__uint_as_float(meta), sv, mv, 0.f);               \
    }

__global__ __launch_bounds__(256) void frcnn_main(
    const float* __restrict__ nms_reg,
    const float* __restrict__ rcnn_reg,
    const float* __restrict__ rcnn_cls,
    const float* __restrict__ bboxes,
    const int* __restrict__ classes,
    const int* __restrict__ reduction,
    float4* __restrict__ part)
{
    __shared__ float4 sbox[NT];
    __shared__ int    scls[NT];
    __shared__ float4 stash[4][32];   // per-wave: 8 tiles x 4 groups
    __shared__ float4 sred[4];

    const int b     = blockIdx.x / BLK_PER_B;
    const int tile0 = (blockIdx.x % BLK_PER_B) * TILES;
    const int grp   = threadIdx.x >> 4;           // 0..15
    const int l     = threadIdx.x & 15;
    const int w     = threadIdx.x >> 6;           // wave in block

    if (threadIdx.x < NT) {
        sbox[threadIdx.x] = ((const float4*)bboxes)[b * NT + threadIdx.x];
        scls[threadIdx.x] = classes[b * NT + threadIdx.x];
    }
    __syncthreads();

    // lane l's 8 target boxes (t = l+16j); areas recomputed inline
    float4 tb[8];
    #pragma unroll
    for (int j = 0; j < 8; ++j) tb[j] = sbox[l + 16 * j];

    const int rv = *reduction;
    float redv;
    if (rv >= 1 && rv <= 65536) redv = (float)rv; // int scalar (expected 16)
    else redv = __int_as_float(rv);               // defensive: f32-encoded
    const float rredv = __builtin_amdgcn_rcpf(redv);

    const bool v5ok = (l < 11);                   // col 80+l < 91

    const size_t pbase = (size_t)b * NR + (size_t)tile0 * 16 + grp;

    // register banks (named scalars only -- rule #20)
    float4 prA, prB, qA, qB;
    float vA4, vA5, vB4, vB5;

    LOADT(A, 0)
    LOADT(B, 1)
    PROC(A, 0)
    LOADT(A, 2)
    PROC(B, 1)
    LOADT(B, 3)
    PROC(A, 2)
    LOADT(A, 4)
    PROC(B, 3)
    LOADT(B, 5)
    PROC(A, 4)
    LOADT(A, 6)
    PROC(B, 5)
    LOADT(B, 7)
    PROC(A, 6)
    PROC(B, 7)

    // ---- deferred epilogue: lanes 0..31 of each wave finalize 32 proposals ----
    // (stash written and read by the SAME wave -> no barrier needed)
    float cnt = 0.f, nll = 0.f, reg = 0.f, corr = 0.f;
    const int L = threadIdx.x & 63;
    if (L < 32) {
        const float4 st = stash[w][L];
        const unsigned int meta = __float_as_uint(st.x);
        if (meta & 128u) {
            const int bidx = (int)(meta & 127u);
            const int cls  = (int)((meta >> 9) & 127u);
            const int tl   = L >> 2;
            const size_t p = (size_t)b * NR + (size_t)(tile0 + tl) * 16
                           + (unsigned)(4 * w + (L & 3));
            const float lc = rcnn_cls[p * NC + cls];   // cache-hot re-load
            cnt  = 1.f;
            nll  = __logf(st.y) - lc;
            corr = (lc == st.z) ? 1.f : 0.f;           // == argmax match (no exact ties)

            const float4 bb = sbox[bidx];
            const float rd0 = rintf(bb.x * rredv) * redv;
            const float rd1 = rintf(bb.y * rredv) * redv;
            const float rd2 = rintf(bb.z * rredv) * redv;
            const float rd3 = rintf(bb.w * rredv) * redv;
            float hgt = rd2 - rd0; if (hgt == 0.f) hgt = 1.f;
            float wid = rd3 - rd1; if (wid == 0.f) wid = 1.f;
            const float rh = __builtin_amdgcn_rcpf(hgt);
            const float rw = __builtin_amdgcn_rcpf(wid);

            const float4 rr = ((const float4*)rcnn_reg)[p];
            reg = smooth_l1(rr.x - (bb.x - rd0) * rh)
                + smooth_l1(rr.y - (bb.y - rd1) * rw)
                + smooth_l1(rr.z - (bb.z - rd2) * rh)
                + smooth_l1(rr.w - (bb.w - rd3) * rw);
        }
    }

    // ---- width-32 butterfly (lanes 0..31 hold the values) ----
    #pragma unroll
    for (int mk = 16; mk; mk >>= 1) {
        cnt  += __shfl_xor(cnt,  mk, 32);
        nll  += __shfl_xor(nll,  mk, 32);
        reg  += __shfl_xor(reg,  mk, 32);
        corr += __shfl_xor(corr, mk, 32);
    }
    if (L == 0) sred[w] = make_float4(cnt, nll, reg, corr);
    __syncthreads();
    if (threadIdx.x == 0) {
        float4 t = make_float4(0.f, 0.f, 0.f, 0.f);
        #pragma unroll
        for (int i = 0; i < 4; ++i) {
            t.x += sred[i].x; t.y += sred[i].y; t.z += sred[i].z; t.w += sred[i].w;
        }
        part[blockIdx.x] = t;
    }
}

// Single-block tree reduce of the 1024 float4 partials + finalize.
__global__ __launch_bounds__(1024) void frcnn_reduce(
    const float4* __restrict__ part, float* __restrict__ out)
{
    __shared__ float4 sw[16];
    float4 s = make_float4(0.f, 0.f, 0.f, 0.f);
    for (int i = threadIdx.x; i < GRID_MAIN; i += 1024) {
        const float4 p = part[i];
        s.x += p.x; s.y += p.y; s.z += p.z; s.w += p.w;
    }
    #pragma unroll
    for (int off = 32; off > 0; off >>= 1) {
        s.x += __shfl_down(s.x, off);
        s.y += __shfl_down(s.y, off);
        s.z += __shfl_down(s.z, off);
        s.w += __shfl_down(s.w, off);
    }
    const int lane = threadIdx.x & 63;
    const int w    = threadIdx.x >> 6;
    if (lane == 0) sw[w] = s;
    __syncthreads();
    if (threadIdx.x == 0) {
        float4 t = make_float4(0.f, 0.f, 0.f, 0.f);
        #pragma unroll
        for (int i = 0; i < 16; ++i) {
            t.x += sw[i].x; t.y += sw[i].y; t.z += sw[i].z; t.w += sw[i].w;
        }
        const float pos   = (t.x > 0.f) ? 1.f : 0.f;
        const float denom = fmaxf(t.x, 1.f);
        out[0] = t.y / denom * pos;   // cls_loss
        out[1] = t.z / denom * pos;   // reg_loss
        out[2] = t.w / denom * pos;   // accuracy
    }
}

extern "C" void kernel_launch(void* const* d_in, const int* in_sizes, int n_in,
                              void* d_out, int out_size, void* d_ws, size_t ws_size,
                              hipStream_t stream) {
    // setup_inputs order: nms_reg, nms_cls(unused), rcnn_reg, rcnn_cls, bboxes, classes, reduction
    const float* nms_reg  = (const float*)d_in[0];
    const float* rcnn_reg = (const float*)d_in[2];
    const float* rcnn_cls = (const float*)d_in[3];
    const float* bboxes   = (const float*)d_in[4];
    const int*   classes  = (const int*)d_in[5];
    const int*   red      = (const int*)d_in[6];

    float4* part = (float4*)d_ws;   // 1024 * 16 B = 16 KiB, fully rewritten each launch

    frcnn_main<<<GRID_MAIN, 256, 0, stream>>>(nms_reg, rcnn_reg, rcnn_cls, bboxes,
                                              classes, red, part);
    frcnn_reduce<<<1, 1024, 0, stream>>>(part, (float*)d_out);
}